// Round 2
// baseline (1333.985 us; speedup 1.0000x reference)
//
#include <hip/hip_runtime.h>
#include <stdint.h>

// alpha^(i-5) for i=0..15 (alpha=0.9); exponent k = d_dst - d_n + 1 in [-5,7]
__device__ __constant__ float c_tab[16] = {
  1.6935087808430286f, 1.5241579027587256f, 1.3717421124828532f,
  1.2345679012345678f, 1.1111111111111112f, 1.0f, 0.9f, 0.81f,
  0.729f, 0.6561f, 0.59049f, 0.531441f, 0.4782969f, 0.43046721f,
  0.387420489f, 0.3486784401f };

// ---- mask dtype probe: int32-encoded bool has all bytes at (i%4)!=0 == 0 ----
__global__ void k_detect(const uint8_t* __restrict__ m, int nbytes,
                         int* __restrict__ flag) {
  int i = blockIdx.x * blockDim.x + threadIdx.x;
  if (i < nbytes && (i & 3) && m[i]) atomicOr(flag, 1);
}

// normalize mask to uint8 0/1 regardless of wire dtype (bool/u8 vs int32)
__global__ void k_norm(const uint8_t* __restrict__ m, uint8_t* __restrict__ m8,
                       int n, const int* __restrict__ flag) {
  int i = blockIdx.x * blockDim.x + threadIdx.x;
  if (i >= n) return;
  int is_u8 = *flag;
  m8[i] = is_u8 ? (m[i] != 0) : (((const int*)m)[i] != 0);
}

// ---- build initial 64-bit reach masks from mask8[n][64] ----
__global__ void k_init_masks(const uint8_t* __restrict__ mask,
                             unsigned long long* __restrict__ R, int N) {
  int n = blockIdx.x * blockDim.x + threadIdx.x;
  if (n >= N) return;
  const unsigned long long* m8 =
      (const unsigned long long*)(mask + (size_t)n * 64);
  unsigned long long r = 0;
#pragma unroll
  for (int q = 0; q < 8; ++q) {
    unsigned long long v = m8[q] & 0x0101010101010101ULL;
    unsigned long long byte = (v * 0x0102040810204080ULL) >> 56;  // gather LSBs
    r |= byte << (8 * q);
  }
  R[n] = r;
}

// ---- one synchronous BFS hop: Rnew[col] |= Rold[row] ----
__global__ void k_bfs(const int* __restrict__ row, const int* __restrict__ col,
                      const unsigned long long* __restrict__ Rold,
                      unsigned long long* __restrict__ Rnew, int E) {
  int e = blockIdx.x * blockDim.x + threadIdx.x;
  if (e >= E) return;
  unsigned long long v = Rold[row[e]];
  if (v) {
    int c = col[e];
    unsigned long long cur = Rnew[c];
    if (v & ~cur) atomicOr(&Rnew[c], v);
  }
}

// ---- recover per-channel hop distance bytes ----
__global__ void k_dist(const unsigned long long* __restrict__ R,
                       uint8_t* __restrict__ dist, int N) {
  int n = blockIdx.x * blockDim.x + threadIdx.x;
  if (n >= N) return;
  unsigned long long nr[6];
#pragma unroll
  for (int h = 0; h < 6; ++h) nr[h] = ~R[(size_t)h * N + n];
  unsigned long long r6 = R[(size_t)6 * N + n];
  unsigned long long* out8 = (unsigned long long*)(dist + (size_t)n * 64);
#pragma unroll
  for (int q = 0; q < 8; ++q) {
    unsigned long long w = 0;
#pragma unroll
    for (int b = 0; b < 8; ++b) {
      int f = q * 8 + b;
      unsigned d = 0;
#pragma unroll
      for (int h = 0; h < 6; ++h) d += (unsigned)((nr[h] >> f) & 1ULL);
      if (!((r6 >> f) & 1ULL)) d = 0;  // unreached -> 0 (matches INF->0)
      w |= (unsigned long long)d << (8 * b);
    }
    out8[q] = w;
  }
}

// ---- CSR build ----
__global__ void k_count(const int* __restrict__ row, int* __restrict__ cnt, int E) {
  int e = blockIdx.x * blockDim.x + threadIdx.x;
  if (e < E) atomicAdd(&cnt[row[e]], 1);
}

// thread-coarsened single-block scan (256 threads, serial chunks)
__global__ void k_scan(const int* __restrict__ cnt, int* __restrict__ row_ptr,
                       int* __restrict__ cursor, int N) {
  __shared__ int sums[256];
  int t = threadIdx.x;
  int chunk = (N + 255) / 256;
  int s0 = t * chunk, s1 = min(s0 + chunk, N);
  int s = 0;
  for (int i = s0; i < s1; ++i) s += cnt[i];
  sums[t] = s;
  __syncthreads();
  for (int off = 1; off < 256; off <<= 1) {
    int v = (t >= off) ? sums[t - off] : 0;
    __syncthreads();
    sums[t] += v;
    __syncthreads();
  }
  int ex = sums[t] - s;  // exclusive prefix of this thread's chunk
  for (int i = s0; i < s1; ++i) {
    row_ptr[i] = ex;
    cursor[i] = ex;
    ex += cnt[i];
  }
  if (t == 255) row_ptr[N] = sums[255];
}

__global__ void k_scatter(const int* __restrict__ row, const int* __restrict__ col,
                          int* __restrict__ cursor, int* __restrict__ dst_csr, int E) {
  int e = blockIdx.x * blockDim.x + threadIdx.x;
  if (e >= E) return;
  int pos = atomicAdd(&cursor[row[e]], 1);
  dst_csr[pos] = col[e];
}

// ---- row-degree of w, inverted (deg_inv factored out of propagation) ----
__global__ void k_deginv(const int* __restrict__ row_ptr, const int* __restrict__ dst_csr,
                         const uint8_t* __restrict__ dist, float* __restrict__ deginv,
                         int N) {
  __shared__ float st[16];
  int t = threadIdx.x;
  if (t < 16) st[t] = c_tab[t];
  __syncthreads();
  int wave = (blockIdx.x * blockDim.x + t) >> 6;
  int lane = t & 63;
  if (wave >= N) return;
  int n = wave;
  int dn = dist[(size_t)n * 64 + lane];
  int s0 = row_ptr[n], s1 = row_ptr[n + 1];
  float acc = 0.f;
  for (int s = s0; s < s1; ++s) {
    int dst = dst_csr[s];
    int dd = dist[(size_t)dst * 64 + lane];
    acc += st[dd - dn + 6];
  }
  deginv[(size_t)n * 64 + lane] = (acc > 0.f) ? (1.f / acc) : 0.f;
}

__global__ void k_init_out(const uint8_t* __restrict__ mask, const float* __restrict__ x,
                           float* __restrict__ o, int total) {
  int i = blockIdx.x * blockDim.x + threadIdx.x;
  if (i < total) o[i] = mask[i] ? x[i] : 0.f;
}

// ---- one propagation step with masked reset ----
__global__ void k_prop(const int* __restrict__ row_ptr, const int* __restrict__ dst_csr,
                       const uint8_t* __restrict__ dist, const float* __restrict__ deginv,
                       const uint8_t* __restrict__ mask, const float* __restrict__ x,
                       const float* __restrict__ o_prev, float* __restrict__ o_new,
                       int N) {
  __shared__ float st[16];
  int t = threadIdx.x;
  if (t < 16) st[t] = c_tab[t];
  __syncthreads();
  int wave = (blockIdx.x * blockDim.x + t) >> 6;
  int lane = t & 63;
  if (wave >= N) return;
  int n = wave;
  size_t ni = (size_t)n * 64 + lane;
  int dn = dist[ni];
  int s0 = row_ptr[n], s1 = row_ptr[n + 1];
  float acc = 0.f;
  for (int s = s0; s < s1; ++s) {
    int dst = dst_csr[s];
    size_t di = (size_t)dst * 64 + lane;
    int dd = dist[di];
    acc += st[dd - dn + 6] * o_prev[di];
  }
  float v = acc * deginv[ni];
  o_new[ni] = mask[ni] ? x[ni] : v;
}

// ---- per-channel mean (sums into musum via atomics) ----
__global__ void k_meansum(const float* __restrict__ o, float* __restrict__ musum, int N) {
  __shared__ float sm[64];
  int t = threadIdx.x;
  if (t < 64) sm[t] = 0.f;
  __syncthreads();
  int lane = t & 63, grp = t >> 6;
  float acc = 0.f;
  for (int n = blockIdx.x * 4 + grp; n < N; n += gridDim.x * 4)
    acc += o[(size_t)n * 64 + lane];
  atomicAdd(&sm[lane], acc);
  __syncthreads();
  if (t < 64) atomicAdd(&musum[t], sm[t]);
}

__global__ void k_mu(const float* __restrict__ musum, float* __restrict__ mu, int N) {
  int t = threadIdx.x;
  if (t < 64) mu[t] = musum[t] / (float)N;
}

// ---- 64x64 centered covariance (4x4 register tiles per thread) ----
__global__ void k_covar(const float* __restrict__ o, const float* __restrict__ mu,
                        float* __restrict__ C, int N) {
  __shared__ float yt[32][64];
  __shared__ float smu[64];
  int t = threadIdx.x;
  if (t < 64) smu[t] = mu[t];
  __syncthreads();
  int i0 = (t >> 4) * 4, j0 = (t & 15) * 4;
  float acc[4][4] = {};
  for (size_t base = (size_t)blockIdx.x * 32; base < (size_t)N;
       base += (size_t)gridDim.x * 32) {
    int rows = min(32, N - (int)base);
    for (int k = t; k < rows * 64; k += 256) {
      int nn = k >> 6, f = k & 63;
      yt[nn][f] = o[(base + nn) * 64 + f] - smu[f];
    }
    __syncthreads();
    for (int nn = 0; nn < rows; ++nn) {
      float yi[4], yj[4];
#pragma unroll
      for (int a = 0; a < 4; ++a) { yi[a] = yt[nn][i0 + a]; yj[a] = yt[nn][j0 + a]; }
#pragma unroll
      for (int a = 0; a < 4; ++a)
#pragma unroll
        for (int b = 0; b < 4; ++b) acc[a][b] += yi[a] * yj[b];
    }
    __syncthreads();
  }
  for (int a = 0; a < 4; ++a)
    for (int b = 0; b < 4; ++b)
      atomicAdd(&C[(size_t)(i0 + a) * 64 + j0 + b], acc[a][b]);
}

__global__ void k_cor(const float* __restrict__ C, float* __restrict__ cor) {
  int idx = blockIdx.x * blockDim.x + threadIdx.x;
  if (idx >= 4096) return;
  int i = idx >> 6, j = idx & 63;
  float d = sqrtf(C[i * 64 + i] * C[j * 64 + j]);
  float v = (i != j && d > 0.f) ? (C[idx] / d) : 0.f;  // nan_to_num + zero diag
  cor[idx] = v;
}

// ---- residual fusion: out = o + 0.5*(1-a^d)*( (a^d*(o-mu)) @ cor ) ----
__global__ void k_fuse(const float* __restrict__ o, const uint8_t* __restrict__ dist,
                       const float* __restrict__ mu, const float* __restrict__ cor,
                       float* __restrict__ out, int N) {
  __shared__ float scor[4096];
  __shared__ float smu[64];
  __shared__ float stab[16];
  int t = threadIdx.x;
  for (int k = t; k < 4096; k += 256) scor[k] = cor[k];
  if (t < 64) smu[t] = mu[t];
  if (t < 16) stab[t] = c_tab[t];
  __syncthreads();
  int lane = t & 63, wv = t >> 6;
  for (int n = blockIdx.x * 4 + wv; n < N; n += gridDim.x * 4) {
    float ov = o[(size_t)n * 64 + lane];
    int d = dist[(size_t)n * 64 + lane];
    float p = stab[d + 5];  // alpha^d
    float a1 = p * (ov - smu[lane]);
    float acc = 0.f;
#pragma unroll 4
    for (int g = 0; g < 64; ++g) {
      float ag = __shfl(a1, g, 64);
      acc += ag * scor[g * 64 + lane];
    }
    out[(size_t)n * 64 + lane] = ov + 0.5f * (1.0f - p) * acc;
  }
}

extern "C" void kernel_launch(void* const* d_in, const int* in_sizes, int n_in,
                              void* d_out, int out_size, void* d_ws, size_t ws_size,
                              hipStream_t stream) {
  const float* x = (const float*)d_in[0];
  const int* ei = (const int*)d_in[1];
  const uint8_t* mask_raw = (const uint8_t*)d_in[2];
  int N = in_sizes[0] / 64;   // 50000
  int E = in_sizes[1] / 2;    // 800000
  const int* row = ei;
  const int* col = ei + E;

  char* w = (char*)d_ws;
  size_t off = 0;
  auto alloc = [&](size_t bytes) -> void* {
    void* p = w + off;
    off += (bytes + 255) & ~(size_t)255;
    return p;
  };
  unsigned long long* R = (unsigned long long*)alloc((size_t)7 * N * 8);
  uint8_t* dist = (uint8_t*)alloc((size_t)N * 64);
  uint8_t* m8 = (uint8_t*)alloc((size_t)N * 64);
  int* dflag = (int*)alloc(256);
  int* cnt = (int*)alloc((size_t)N * 4);
  int* row_ptr = (int*)alloc((size_t)(N + 1) * 4);
  int* cursor = (int*)alloc((size_t)N * 4);
  int* dst_csr = (int*)alloc((size_t)E * 4);
  float* deginv = (float*)alloc((size_t)N * 64 * 4);
  float* oA = (float*)alloc((size_t)N * 64 * 4);
  float* oB = (float*)alloc((size_t)N * 64 * 4);
  float* musum = (float*)alloc(256);
  float* mu = (float*)alloc(256);
  float* C = (float*)alloc(64 * 64 * 4);
  float* cor = (float*)alloc(64 * 64 * 4);

  int gN = (N + 255) / 256;
  int gE = (E + 255) / 256;
  int total = N * 64;
  int gT = (total + 255) / 256;  // 12500 blocks, one wave per node

  // 0. normalize mask dtype (bool/u8 wire format vs int32)
  hipMemsetAsync(dflag, 0, 4, stream);
  k_detect<<<gT, 256, 0, stream>>>(mask_raw, total, dflag);
  k_norm<<<gT, 256, 0, stream>>>(mask_raw, m8, total, dflag);

  // 1. per-channel BFS via 64-bit reach masks
  k_init_masks<<<gN, 256, 0, stream>>>(m8, R, N);
  for (int h = 0; h < 6; ++h) {
    hipMemcpyAsync(R + (size_t)(h + 1) * N, R + (size_t)h * N, (size_t)N * 8,
                   hipMemcpyDeviceToDevice, stream);
    k_bfs<<<gE, 256, 0, stream>>>(row, col, R + (size_t)h * N,
                                  R + (size_t)(h + 1) * N, E);
  }
  k_dist<<<gN, 256, 0, stream>>>(R, dist, N);

  // 2. CSR by row
  hipMemsetAsync(cnt, 0, (size_t)N * 4, stream);
  k_count<<<gE, 256, 0, stream>>>(row, cnt, E);
  k_scan<<<1, 256, 0, stream>>>(cnt, row_ptr, cursor, N);
  k_scatter<<<gE, 256, 0, stream>>>(row, col, cursor, dst_csr, E);

  // 3. degree normalization
  k_deginv<<<gT, 256, 0, stream>>>(row_ptr, dst_csr, dist, deginv, N);

  // 4. 8 propagation iterations with masked reset
  k_init_out<<<gT, 256, 0, stream>>>(m8, x, oA, total);
  float* src = oA;
  float* dst = oB;
  for (int it = 0; it < 8; ++it) {
    k_prop<<<gT, 256, 0, stream>>>(row_ptr, dst_csr, dist, deginv, m8, x, src,
                                   dst, N);
    float* tmp = src; src = dst; dst = tmp;
  }
  // final result is in src

  // 5. correlation
  hipMemsetAsync(musum, 0, 256, stream);
  k_meansum<<<256, 256, 0, stream>>>(src, musum, N);
  k_mu<<<1, 64, 0, stream>>>(musum, mu, N);
  hipMemsetAsync(C, 0, 64 * 64 * 4, stream);
  k_covar<<<128, 256, 0, stream>>>(src, mu, C, N);
  k_cor<<<16, 256, 0, stream>>>(C, cor);

  // 6. fusion -> d_out
  k_fuse<<<256, 256, 0, stream>>>(src, dist, mu, cor, (float*)d_out, N);
}

// Round 3
// 845.867 us; speedup vs baseline: 1.5771x; 1.5771x over previous
//
#include <hip/hip_runtime.h>
#include <stdint.h>

// alpha^(i-5) for i=0..15 (alpha=0.9); exponent k = d_dst - d_n + 1 in [-5,7]
__device__ __constant__ float c_tab[16] = {
  1.6935087808430286f, 1.5241579027587256f, 1.3717421124828532f,
  1.2345679012345678f, 1.1111111111111112f, 1.0f, 0.9f, 0.81f,
  0.729f, 0.6561f, 0.59049f, 0.531441f, 0.4782969f, 0.43046721f,
  0.387420489f, 0.3486784401f };

// ---- mask dtype probe: int32-encoded bool has all bytes at (i%4)!=0 == 0 ----
__global__ void k_detect(const uint8_t* __restrict__ m, int nbytes,
                         int* __restrict__ flag) {
  int i = blockIdx.x * blockDim.x + threadIdx.x;
  if (i < nbytes && (i & 3) && m[i]) atomicOr(flag, 1);
}

// normalize mask to uint8 0/1 regardless of wire dtype (bool/u8 vs int32)
__global__ void k_norm(const uint8_t* __restrict__ m, uint8_t* __restrict__ m8,
                       int n, const int* __restrict__ flag) {
  int i = blockIdx.x * blockDim.x + threadIdx.x;
  if (i >= n) return;
  int is_u8 = *flag;
  m8[i] = is_u8 ? (m[i] != 0) : (((const int*)m)[i] != 0);
}

// ---- build initial 64-bit reach masks from mask8[n][64] ----
__global__ void k_init_masks(const uint8_t* __restrict__ mask,
                             unsigned long long* __restrict__ R, int N) {
  int n = blockIdx.x * blockDim.x + threadIdx.x;
  if (n >= N) return;
  const unsigned long long* m8 =
      (const unsigned long long*)(mask + (size_t)n * 64);
  unsigned long long r = 0;
#pragma unroll
  for (int q = 0; q < 8; ++q) {
    unsigned long long v = m8[q] & 0x0101010101010101ULL;
    unsigned long long byte = (v * 0x0102040810204080ULL) >> 56;  // gather LSBs
    r |= byte << (8 * q);
  }
  R[n] = r;
}

// ---- one synchronous BFS hop: Rnew[col] |= Rold[row] ----
__global__ void k_bfs(const int* __restrict__ row, const int* __restrict__ col,
                      const unsigned long long* __restrict__ Rold,
                      unsigned long long* __restrict__ Rnew, int E) {
  int e = blockIdx.x * blockDim.x + threadIdx.x;
  if (e >= E) return;
  unsigned long long v = Rold[row[e]];
  if (v) {
    int c = col[e];
    unsigned long long cur = Rnew[c];
    if (v & ~cur) atomicOr(&Rnew[c], v);
  }
}

// ---- recover per-channel hop distance bytes ----
__global__ void k_dist(const unsigned long long* __restrict__ R,
                       uint8_t* __restrict__ dist, int N) {
  int n = blockIdx.x * blockDim.x + threadIdx.x;
  if (n >= N) return;
  unsigned long long nr[6];
#pragma unroll
  for (int h = 0; h < 6; ++h) nr[h] = ~R[(size_t)h * N + n];
  unsigned long long r6 = R[(size_t)6 * N + n];
  unsigned long long* out8 = (unsigned long long*)(dist + (size_t)n * 64);
#pragma unroll
  for (int q = 0; q < 8; ++q) {
    unsigned long long w = 0;
#pragma unroll
    for (int b = 0; b < 8; ++b) {
      int f = q * 8 + b;
      unsigned d = 0;
#pragma unroll
      for (int h = 0; h < 6; ++h) d += (unsigned)((nr[h] >> f) & 1ULL);
      if (!((r6 >> f) & 1ULL)) d = 0;  // unreached -> 0 (matches INF->0)
      w |= (unsigned long long)d << (8 * b);
    }
    out8[q] = w;
  }
}

// ---- CSR build ----
__global__ void k_count(const int* __restrict__ row, int* __restrict__ cnt, int E) {
  int e = blockIdx.x * blockDim.x + threadIdx.x;
  if (e < E) atomicAdd(&cnt[row[e]], 1);
}

// hierarchical scan, phase 1: per-block (256-elem chunk) sums
__global__ void k_bsum(const int* __restrict__ cnt, int* __restrict__ bsum, int N) {
  __shared__ int sm[256];
  int b = blockIdx.x, t = threadIdx.x;
  int i = b * 256 + t;
  int v = (i < N) ? cnt[i] : 0;
  sm[t] = v;
  __syncthreads();
  for (int off = 128; off > 0; off >>= 1) {
    if (t < off) sm[t] += sm[t + off];
    __syncthreads();
  }
  if (t == 0) bsum[b] = sm[0];
}

// phase 2: single-block exclusive scan of block sums (NB <= 256)
__global__ void k_bscan(const int* __restrict__ bsum, int* __restrict__ ebsum,
                        int* __restrict__ row_ptr_N, int NB) {
  __shared__ int sm[256];
  int t = threadIdx.x;
  int v = (t < NB) ? bsum[t] : 0;
  sm[t] = v;
  __syncthreads();
  for (int off = 1; off < 256; off <<= 1) {
    int tv = (t >= off) ? sm[t - off] : 0;
    __syncthreads();
    sm[t] += tv;
    __syncthreads();
  }
  if (t < NB) ebsum[t] = sm[t] - v;
  if (t == 255) *row_ptr_N = sm[255];
}

// phase 3: per-chunk exclusive scan + chunk offset
__global__ void k_chscan(const int* __restrict__ cnt, const int* __restrict__ ebsum,
                         int* __restrict__ row_ptr, int* __restrict__ cursor, int N) {
  __shared__ int sm[256];
  int b = blockIdx.x, t = threadIdx.x;
  int i = b * 256 + t;
  int v = (i < N) ? cnt[i] : 0;
  sm[t] = v;
  __syncthreads();
  for (int off = 1; off < 256; off <<= 1) {
    int tv = (t >= off) ? sm[t - off] : 0;
    __syncthreads();
    sm[t] += tv;
    __syncthreads();
  }
  if (i < N) {
    int ex = ebsum[b] + sm[t] - v;
    row_ptr[i] = ex;
    cursor[i] = ex;
  }
}

__global__ void k_scatter(const int* __restrict__ row, const int* __restrict__ col,
                          int* __restrict__ cursor, int* __restrict__ dst_csr, int E) {
  int e = blockIdx.x * blockDim.x + threadIdx.x;
  if (e >= E) return;
  int pos = atomicAdd(&cursor[row[e]], 1);
  dst_csr[pos] = col[e];
}

// ---- row-degree of w, inverted (deg_inv factored out of propagation) ----
__global__ void k_deginv(const int* __restrict__ row_ptr, const int* __restrict__ dst_csr,
                         const uint8_t* __restrict__ dist, float* __restrict__ deginv,
                         int N) {
  __shared__ float st[16];
  int t = threadIdx.x;
  if (t < 16) st[t] = c_tab[t];
  __syncthreads();
  int wave = (blockIdx.x * blockDim.x + t) >> 6;
  int lane = t & 63;
  if (wave >= N) return;
  int n = wave;
  int dn = dist[(size_t)n * 64 + lane];
  int s0 = row_ptr[n], s1 = row_ptr[n + 1];
  float acc = 0.f;
#pragma unroll 4
  for (int s = s0; s < s1; ++s) {
    int dst = dst_csr[s];
    int dd = dist[(size_t)dst * 64 + lane];
    acc += st[dd - dn + 6];
  }
  deginv[(size_t)n * 64 + lane] = (acc > 0.f) ? (1.f / acc) : 0.f;
}

__global__ void k_init_out(const uint8_t* __restrict__ mask, const float* __restrict__ x,
                           float* __restrict__ o, int total) {
  int i = blockIdx.x * blockDim.x + threadIdx.x;
  if (i < total) o[i] = mask[i] ? x[i] : 0.f;
}

// ---- one propagation step with masked reset ----
__global__ void k_prop(const int* __restrict__ row_ptr, const int* __restrict__ dst_csr,
                       const uint8_t* __restrict__ dist, const float* __restrict__ deginv,
                       const uint8_t* __restrict__ mask, const float* __restrict__ x,
                       const float* __restrict__ o_prev, float* __restrict__ o_new,
                       int N) {
  __shared__ float st[16];
  int t = threadIdx.x;
  if (t < 16) st[t] = c_tab[t];
  __syncthreads();
  int wave = (blockIdx.x * blockDim.x + t) >> 6;
  int lane = t & 63;
  if (wave >= N) return;
  int n = wave;
  size_t ni = (size_t)n * 64 + lane;
  int dn = dist[ni];
  int s0 = row_ptr[n], s1 = row_ptr[n + 1];
  float acc = 0.f;
#pragma unroll 4
  for (int s = s0; s < s1; ++s) {
    int dst = dst_csr[s];
    size_t di = (size_t)dst * 64 + lane;
    int dd = dist[di];
    acc += st[dd - dn + 6] * o_prev[di];
  }
  float v = acc * deginv[ni];
  o_new[ni] = mask[ni] ? x[ni] : v;
}

// ---- per-channel mean (sums into musum via atomics) ----
__global__ void k_meansum(const float* __restrict__ o, float* __restrict__ musum, int N) {
  __shared__ float sm[64];
  int t = threadIdx.x;
  if (t < 64) sm[t] = 0.f;
  __syncthreads();
  int lane = t & 63, grp = t >> 6;
  float acc = 0.f;
  for (int n = blockIdx.x * 4 + grp; n < N; n += gridDim.x * 4)
    acc += o[(size_t)n * 64 + lane];
  atomicAdd(&sm[lane], acc);
  __syncthreads();
  if (t < 64) atomicAdd(&musum[t], sm[t]);
}

__global__ void k_mu(const float* __restrict__ musum, float* __restrict__ mu, int N) {
  int t = threadIdx.x;
  if (t < 64) mu[t] = musum[t] / (float)N;
}

// ---- 64x64 centered covariance (4x4 register tiles per thread) ----
__global__ void k_covar(const float* __restrict__ o, const float* __restrict__ mu,
                        float* __restrict__ C, int N) {
  __shared__ float yt[32][64];
  __shared__ float smu[64];
  int t = threadIdx.x;
  if (t < 64) smu[t] = mu[t];
  __syncthreads();
  int i0 = (t >> 4) * 4, j0 = (t & 15) * 4;
  float acc[4][4] = {};
  for (size_t base = (size_t)blockIdx.x * 32; base < (size_t)N;
       base += (size_t)gridDim.x * 32) {
    int rows = min(32, N - (int)base);
    for (int k = t; k < rows * 64; k += 256) {
      int nn = k >> 6, f = k & 63;
      yt[nn][f] = o[(base + nn) * 64 + f] - smu[f];
    }
    __syncthreads();
    for (int nn = 0; nn < rows; ++nn) {
      float yi[4], yj[4];
#pragma unroll
      for (int a = 0; a < 4; ++a) { yi[a] = yt[nn][i0 + a]; yj[a] = yt[nn][j0 + a]; }
#pragma unroll
      for (int a = 0; a < 4; ++a)
#pragma unroll
        for (int b = 0; b < 4; ++b) acc[a][b] += yi[a] * yj[b];
    }
    __syncthreads();
  }
  for (int a = 0; a < 4; ++a)
    for (int b = 0; b < 4; ++b)
      atomicAdd(&C[(size_t)(i0 + a) * 64 + j0 + b], acc[a][b]);
}

__global__ void k_cor(const float* __restrict__ C, float* __restrict__ cor) {
  int idx = blockIdx.x * blockDim.x + threadIdx.x;
  if (idx >= 4096) return;
  int i = idx >> 6, j = idx & 63;
  float d = sqrtf(C[i * 64 + i] * C[j * 64 + j]);
  float v = (i != j && d > 0.f) ? (C[idx] / d) : 0.f;  // nan_to_num + zero diag
  cor[idx] = v;
}

// ---- residual fusion: out = o + 0.5*(1-a^d)*( (a^d*(o-mu)) @ cor ) ----
__global__ void k_fuse(const float* __restrict__ o, const uint8_t* __restrict__ dist,
                       const float* __restrict__ mu, const float* __restrict__ cor,
                       float* __restrict__ out, int N) {
  __shared__ float scor[4096];
  __shared__ float smu[64];
  __shared__ float stab[16];
  int t = threadIdx.x;
  for (int k = t; k < 4096; k += 256) scor[k] = cor[k];
  if (t < 64) smu[t] = mu[t];
  if (t < 16) stab[t] = c_tab[t];
  __syncthreads();
  int lane = t & 63, wv = t >> 6;
  for (int n = blockIdx.x * 4 + wv; n < N; n += gridDim.x * 4) {
    float ov = o[(size_t)n * 64 + lane];
    int d = dist[(size_t)n * 64 + lane];
    float p = stab[d + 5];  // alpha^d
    float a1 = p * (ov - smu[lane]);
    float acc = 0.f;
#pragma unroll 4
    for (int g = 0; g < 64; ++g) {
      float ag = __shfl(a1, g, 64);
      acc += ag * scor[g * 64 + lane];
    }
    out[(size_t)n * 64 + lane] = ov + 0.5f * (1.0f - p) * acc;
  }
}

extern "C" void kernel_launch(void* const* d_in, const int* in_sizes, int n_in,
                              void* d_out, int out_size, void* d_ws, size_t ws_size,
                              hipStream_t stream) {
  const float* x = (const float*)d_in[0];
  const int* ei = (const int*)d_in[1];
  const uint8_t* mask_raw = (const uint8_t*)d_in[2];
  int N = in_sizes[0] / 64;   // 50000
  int E = in_sizes[1] / 2;    // 800000
  const int* row = ei;
  const int* col = ei + E;

  char* w = (char*)d_ws;
  size_t off = 0;
  auto alloc = [&](size_t bytes) -> void* {
    void* p = w + off;
    off += (bytes + 255) & ~(size_t)255;
    return p;
  };
  unsigned long long* R = (unsigned long long*)alloc((size_t)7 * N * 8);
  uint8_t* dist = (uint8_t*)alloc((size_t)N * 64);
  uint8_t* m8 = (uint8_t*)alloc((size_t)N * 64);
  int* dflag = (int*)alloc(256);
  int* cnt = (int*)alloc((size_t)N * 4);
  int* row_ptr = (int*)alloc((size_t)(N + 1) * 4);
  int* cursor = (int*)alloc((size_t)N * 4);
  int* dst_csr = (int*)alloc((size_t)E * 4);
  int* bsum = (int*)alloc(256 * 4);
  int* ebsum = (int*)alloc(256 * 4);
  float* deginv = (float*)alloc((size_t)N * 64 * 4);
  float* oA = (float*)alloc((size_t)N * 64 * 4);
  float* oB = (float*)alloc((size_t)N * 64 * 4);
  float* musum = (float*)alloc(256);
  float* mu = (float*)alloc(256);
  float* C = (float*)alloc(64 * 64 * 4);
  float* cor = (float*)alloc(64 * 64 * 4);

  int gN = (N + 255) / 256;
  int gE = (E + 255) / 256;
  int total = N * 64;
  int gT = (total + 255) / 256;  // 12500 blocks, one wave per node
  int NB = (N + 255) / 256;      // 196 scan chunks (<=256 required)

  // 0. normalize mask dtype (bool/u8 wire format vs int32)
  hipMemsetAsync(dflag, 0, 4, stream);
  k_detect<<<gT, 256, 0, stream>>>(mask_raw, total, dflag);
  k_norm<<<gT, 256, 0, stream>>>(mask_raw, m8, total, dflag);

  // 1. per-channel BFS via 64-bit reach masks
  k_init_masks<<<gN, 256, 0, stream>>>(m8, R, N);
  for (int h = 0; h < 6; ++h) {
    hipMemcpyAsync(R + (size_t)(h + 1) * N, R + (size_t)h * N, (size_t)N * 8,
                   hipMemcpyDeviceToDevice, stream);
    k_bfs<<<gE, 256, 0, stream>>>(row, col, R + (size_t)h * N,
                                  R + (size_t)(h + 1) * N, E);
  }
  k_dist<<<gN, 256, 0, stream>>>(R, dist, N);

  // 2. CSR by row (hierarchical 3-phase scan)
  hipMemsetAsync(cnt, 0, (size_t)N * 4, stream);
  k_count<<<gE, 256, 0, stream>>>(row, cnt, E);
  k_bsum<<<NB, 256, 0, stream>>>(cnt, bsum, N);
  k_bscan<<<1, 256, 0, stream>>>(bsum, ebsum, row_ptr + N, NB);
  k_chscan<<<NB, 256, 0, stream>>>(cnt, ebsum, row_ptr, cursor, N);
  k_scatter<<<gE, 256, 0, stream>>>(row, col, cursor, dst_csr, E);

  // 3. degree normalization
  k_deginv<<<gT, 256, 0, stream>>>(row_ptr, dst_csr, dist, deginv, N);

  // 4. 8 propagation iterations with masked reset
  k_init_out<<<gT, 256, 0, stream>>>(m8, x, oA, total);
  float* src = oA;
  float* dst = oB;
  for (int it = 0; it < 8; ++it) {
    k_prop<<<gT, 256, 0, stream>>>(row_ptr, dst_csr, dist, deginv, m8, x, src,
                                   dst, N);
    float* tmp = src; src = dst; dst = tmp;
  }
  // final result is in src

  // 5. correlation
  hipMemsetAsync(musum, 0, 256, stream);
  k_meansum<<<256, 256, 0, stream>>>(src, musum, N);
  k_mu<<<1, 64, 0, stream>>>(musum, mu, N);
  hipMemsetAsync(C, 0, 64 * 64 * 4, stream);
  k_covar<<<128, 256, 0, stream>>>(src, mu, C, N);
  k_cor<<<16, 256, 0, stream>>>(C, cor);

  // 6. fusion -> d_out
  k_fuse<<<256, 256, 0, stream>>>(src, dist, mu, cor, (float*)d_out, N);
}

// Round 4
// 659.248 us; speedup vs baseline: 2.0235x; 1.2831x over previous
//
#include <hip/hip_runtime.h>
#include <stdint.h>

// alpha^(i-5) for i=0..15 (alpha=0.9); pw = alpha^d uses c_tab[d+5]
__device__ __constant__ float c_tab[16] = {
  1.6935087808430286f, 1.5241579027587256f, 1.3717421124828532f,
  1.2345679012345678f, 1.1111111111111112f, 1.0f, 0.9f, 0.81f,
  0.729f, 0.6561f, 0.59049f, 0.531441f, 0.4782969f, 0.43046721f,
  0.387420489f, 0.3486784401f };

// ---- mask dtype probe: int32-encoded bool has all bytes at (i%4)!=0 == 0 ----
__global__ void k_detect(const uint8_t* __restrict__ m, int nbytes,
                         int* __restrict__ flag) {
  int i = blockIdx.x * blockDim.x + threadIdx.x;
  if (i < nbytes && (i & 3) && m[i]) atomicOr(flag, 1);
}

__global__ void k_norm(const uint8_t* __restrict__ m, uint8_t* __restrict__ m8,
                       int n, const int* __restrict__ flag) {
  int i = blockIdx.x * blockDim.x + threadIdx.x;
  if (i >= n) return;
  int is_u8 = *flag;
  m8[i] = is_u8 ? (m[i] != 0) : (((const int*)m)[i] != 0);
}

// ---- build initial 64-bit reach masks from mask8[n][64] ----
__global__ void k_init_masks(const uint8_t* __restrict__ mask,
                             unsigned long long* __restrict__ R, int N) {
  int n = blockIdx.x * blockDim.x + threadIdx.x;
  if (n >= N) return;
  const unsigned long long* m8 =
      (const unsigned long long*)(mask + (size_t)n * 64);
  unsigned long long r = 0;
#pragma unroll
  for (int q = 0; q < 8; ++q) {
    unsigned long long v = m8[q] & 0x0101010101010101ULL;
    unsigned long long byte = (v * 0x0102040810204080ULL) >> 56;
    r |= byte << (8 * q);
  }
  R[n] = r;
}

// ---- pull-mode BFS hop: Rnew[n] = Rold[n] | OR_{dst in CSR[n]} Rold[dst] ----
__global__ void k_bfs_pull(const int* __restrict__ row_ptr,
                           const int* __restrict__ dst_csr,
                           const unsigned long long* __restrict__ Rold,
                           unsigned long long* __restrict__ Rnew, int N) {
  int n = blockIdx.x * blockDim.x + threadIdx.x;
  if (n >= N) return;
  unsigned long long r = Rold[n];
  int s = row_ptr[n], s1 = row_ptr[n + 1];
  for (; s + 4 <= s1; s += 4) {
    int d0 = dst_csr[s], d1 = dst_csr[s + 1], d2 = dst_csr[s + 2], d3 = dst_csr[s + 3];
    unsigned long long r0 = Rold[d0] | Rold[d1];
    unsigned long long r1 = Rold[d2] | Rold[d3];
    r |= r0 | r1;
  }
  for (; s < s1; ++s) r |= Rold[dst_csr[s]];
  Rnew[n] = r;
}

// ---- dist -> pw = alpha^d directly (wave per node, lane = channel) ----
__global__ void k_distpw(const unsigned long long* __restrict__ R,
                         float* __restrict__ pw, int N) {
  int wave = (blockIdx.x * blockDim.x + threadIdx.x) >> 6;
  int lane = threadIdx.x & 63;
  if (wave >= N) return;
  int d = 0;
#pragma unroll
  for (int h = 0; h < 6; ++h)
    d += (int)((~R[(size_t)h * N + wave] >> lane) & 1ULL);
  if (!((R[(size_t)6 * N + wave] >> lane) & 1ULL)) d = 0;  // unreached -> 0
  pw[(size_t)wave * 64 + lane] = c_tab[d + 5];
}

// ---- CSR build ----
__global__ void k_count(const int* __restrict__ row, int* __restrict__ cnt, int E) {
  int e = blockIdx.x * blockDim.x + threadIdx.x;
  if (e < E) atomicAdd(&cnt[row[e]], 1);
}

__global__ void k_bsum(const int* __restrict__ cnt, int* __restrict__ bsum, int N) {
  __shared__ int sm[256];
  int b = blockIdx.x, t = threadIdx.x;
  int i = b * 256 + t;
  int v = (i < N) ? cnt[i] : 0;
  sm[t] = v;
  __syncthreads();
  for (int off = 128; off > 0; off >>= 1) {
    if (t < off) sm[t] += sm[t + off];
    __syncthreads();
  }
  if (t == 0) bsum[b] = sm[0];
}

__global__ void k_bscan(const int* __restrict__ bsum, int* __restrict__ ebsum,
                        int* __restrict__ row_ptr_N, int NB) {
  __shared__ int sm[256];
  int t = threadIdx.x;
  int v = (t < NB) ? bsum[t] : 0;
  sm[t] = v;
  __syncthreads();
  for (int off = 1; off < 256; off <<= 1) {
    int tv = (t >= off) ? sm[t - off] : 0;
    __syncthreads();
    sm[t] += tv;
    __syncthreads();
  }
  if (t < NB) ebsum[t] = sm[t] - v;
  if (t == 255) *row_ptr_N = sm[255];
}

__global__ void k_chscan(const int* __restrict__ cnt, const int* __restrict__ ebsum,
                         int* __restrict__ row_ptr, int* __restrict__ cursor, int N) {
  __shared__ int sm[256];
  int b = blockIdx.x, t = threadIdx.x;
  int i = b * 256 + t;
  int v = (i < N) ? cnt[i] : 0;
  sm[t] = v;
  __syncthreads();
  for (int off = 1; off < 256; off <<= 1) {
    int tv = (t >= off) ? sm[t - off] : 0;
    __syncthreads();
    sm[t] += tv;
    __syncthreads();
  }
  if (i < N) {
    int ex = ebsum[b] + sm[t] - v;
    row_ptr[i] = ex;
    cursor[i] = ex;
  }
}

__global__ void k_scatter(const int* __restrict__ row, const int* __restrict__ col,
                          int* __restrict__ cursor, int* __restrict__ dst_csr, int E) {
  int e = blockIdx.x * blockDim.x + threadIdx.x;
  if (e >= E) return;
  int pos = atomicAdd(&cursor[row[e]], 1);
  dst_csr[pos] = col[e];
}

// ---- sinv[n][f] = 1 / sum_{dst in CSR[n]} pw[dst][f] ----
__global__ void k_sinv(const int* __restrict__ row_ptr, const int* __restrict__ dst_csr,
                       const float* __restrict__ pw, float* __restrict__ sinv, int N) {
  int wave = (blockIdx.x * blockDim.x + threadIdx.x) >> 6;
  int lane = threadIdx.x & 63;
  if (wave >= N) return;
  int s = row_ptr[wave], s1 = row_ptr[wave + 1];
  float acc = 0.f;
  for (; s + 4 <= s1; s += 4) {
    int d0 = dst_csr[s], d1 = dst_csr[s + 1], d2 = dst_csr[s + 2], d3 = dst_csr[s + 3];
    acc += pw[(size_t)d0 * 64 + lane] + pw[(size_t)d1 * 64 + lane] +
           pw[(size_t)d2 * 64 + lane] + pw[(size_t)d3 * 64 + lane];
  }
  for (; s < s1; ++s) acc += pw[(size_t)dst_csr[s] * 64 + lane];
  sinv[(size_t)wave * 64 + lane] = (acc > 0.f) ? (1.f / acc) : 0.f;
}

// ---- z0 = pw * (mask ? x : 0) ----
__global__ void k_init_z(const uint8_t* __restrict__ mask, const float* __restrict__ x,
                         const float* __restrict__ pw, float* __restrict__ z, int total) {
  int i = blockIdx.x * blockDim.x + threadIdx.x;
  if (i < total) z[i] = mask[i] ? pw[i] * x[i] : 0.f;
}

// ---- propagation on z-state: v = sinv * sum z[dst]; o = mask?x:v;
//      write z' = pw*o (or o itself on the final pass) ----
__global__ void k_prop_z(const int* __restrict__ row_ptr, const int* __restrict__ dst_csr,
                         const float* __restrict__ sinv, const float* __restrict__ pw,
                         const uint8_t* __restrict__ mask, const float* __restrict__ x,
                         const float* __restrict__ z_prev, float* __restrict__ out,
                         int N, int write_o) {
  int wave = (blockIdx.x * blockDim.x + threadIdx.x) >> 6;
  int lane = threadIdx.x & 63;
  if (wave >= N) return;
  size_t ni = (size_t)wave * 64 + lane;
  int s = row_ptr[wave], s1 = row_ptr[wave + 1];
  float acc = 0.f;
  for (; s + 4 <= s1; s += 4) {
    int d0 = dst_csr[s], d1 = dst_csr[s + 1], d2 = dst_csr[s + 2], d3 = dst_csr[s + 3];
    float a0 = z_prev[(size_t)d0 * 64 + lane] + z_prev[(size_t)d1 * 64 + lane];
    float a1 = z_prev[(size_t)d2 * 64 + lane] + z_prev[(size_t)d3 * 64 + lane];
    acc += a0 + a1;
  }
  for (; s < s1; ++s) acc += z_prev[(size_t)dst_csr[s] * 64 + lane];
  float v = acc * sinv[ni];
  float ov = mask[ni] ? x[ni] : v;
  out[ni] = write_o ? ov : pw[ni] * ov;
}

// ---- per-channel mean ----
__global__ void k_meansum(const float* __restrict__ o, float* __restrict__ musum, int N) {
  __shared__ float sm[64];
  int t = threadIdx.x;
  if (t < 64) sm[t] = 0.f;
  __syncthreads();
  int lane = t & 63, grp = t >> 6;
  float acc = 0.f;
  for (int n = blockIdx.x * 4 + grp; n < N; n += gridDim.x * 4)
    acc += o[(size_t)n * 64 + lane];
  atomicAdd(&sm[lane], acc);
  __syncthreads();
  if (t < 64) atomicAdd(&musum[t], sm[t]);
}

__global__ void k_mu(const float* __restrict__ musum, float* __restrict__ mu, int N) {
  int t = threadIdx.x;
  if (t < 64) mu[t] = musum[t] / (float)N;
}

// ---- 64x64 centered covariance ----
__global__ void k_covar(const float* __restrict__ o, const float* __restrict__ mu,
                        float* __restrict__ C, int N) {
  __shared__ float yt[32][64];
  __shared__ float smu[64];
  int t = threadIdx.x;
  if (t < 64) smu[t] = mu[t];
  __syncthreads();
  int i0 = (t >> 4) * 4, j0 = (t & 15) * 4;
  float acc[4][4] = {};
  for (size_t base = (size_t)blockIdx.x * 32; base < (size_t)N;
       base += (size_t)gridDim.x * 32) {
    int rows = min(32, N - (int)base);
    for (int k = t; k < rows * 64; k += 256) {
      int nn = k >> 6, f = k & 63;
      yt[nn][f] = o[(base + nn) * 64 + f] - smu[f];
    }
    __syncthreads();
    for (int nn = 0; nn < rows; ++nn) {
      float yi[4], yj[4];
#pragma unroll
      for (int a = 0; a < 4; ++a) { yi[a] = yt[nn][i0 + a]; yj[a] = yt[nn][j0 + a]; }
#pragma unroll
      for (int a = 0; a < 4; ++a)
#pragma unroll
        for (int b = 0; b < 4; ++b) acc[a][b] += yi[a] * yj[b];
    }
    __syncthreads();
  }
  for (int a = 0; a < 4; ++a)
    for (int b = 0; b < 4; ++b)
      atomicAdd(&C[(size_t)(i0 + a) * 64 + j0 + b], acc[a][b]);
}

__global__ void k_cor(const float* __restrict__ C, float* __restrict__ cor) {
  int idx = blockIdx.x * blockDim.x + threadIdx.x;
  if (idx >= 4096) return;
  int i = idx >> 6, j = idx & 63;
  float d = sqrtf(C[i * 64 + i] * C[j * 64 + j]);
  float v = (i != j && d > 0.f) ? (C[idx] / d) : 0.f;
  cor[idx] = v;
}

// ---- fusion as tiled GEMM: out = o + 0.5*(1-pw)*((pw*(o-mu)) @ cor) ----
// block: 64-node x 64-ch tile; thread: 4x4 register tile; K=64
__global__ void k_fuse2(const float* __restrict__ o, const float* __restrict__ pw,
                        const float* __restrict__ mu, const float* __restrict__ cor,
                        float* __restrict__ out, int N) {
  __shared__ float a1t[64][65];
  __shared__ float scor[64][65];
  __shared__ float smu[64];
  int t = threadIdx.x;
  int nbase = blockIdx.x * 64;
  if (t < 64) smu[t] = mu[t];
#pragma unroll
  for (int j = 0; j < 16; ++j) {
    int idx = t + 256 * j;
    scor[idx >> 6][idx & 63] = cor[idx];
  }
  __syncthreads();
#pragma unroll
  for (int j = 0; j < 16; ++j) {
    int idx = t + 256 * j;
    int r = idx >> 6, c = idx & 63;
    int n = nbase + r;
    float val = 0.f;
    if (n < N) {
      size_t g = (size_t)n * 64 + c;
      val = pw[g] * (o[g] - smu[c]);
    }
    a1t[r][c] = val;
  }
  __syncthreads();
  int tr = (t >> 4) * 4, tc = (t & 15) * 4;
  float acc[4][4] = {};
  for (int k = 0; k < 64; ++k) {
    float a[4], b[4];
#pragma unroll
    for (int i = 0; i < 4; ++i) a[i] = a1t[tr + i][k];
#pragma unroll
    for (int j = 0; j < 4; ++j) b[j] = scor[k][tc + j];
#pragma unroll
    for (int i = 0; i < 4; ++i)
#pragma unroll
      for (int j = 0; j < 4; ++j) acc[i][j] += a[i] * b[j];
  }
#pragma unroll
  for (int i = 0; i < 4; ++i) {
    int n = nbase + tr + i;
    if (n < N) {
#pragma unroll
      for (int j = 0; j < 4; ++j) {
        size_t g = (size_t)n * 64 + tc + j;
        float p = pw[g];
        out[g] = o[g] + 0.5f * (1.f - p) * acc[i][j];
      }
    }
  }
}

extern "C" void kernel_launch(void* const* d_in, const int* in_sizes, int n_in,
                              void* d_out, int out_size, void* d_ws, size_t ws_size,
                              hipStream_t stream) {
  const float* x = (const float*)d_in[0];
  const int* ei = (const int*)d_in[1];
  const uint8_t* mask_raw = (const uint8_t*)d_in[2];
  int N = in_sizes[0] / 64;   // 50000
  int E = in_sizes[1] / 2;    // 800000
  const int* row = ei;
  const int* col = ei + E;

  char* w = (char*)d_ws;
  size_t off = 0;
  auto alloc = [&](size_t bytes) -> void* {
    void* p = w + off;
    off += (bytes + 255) & ~(size_t)255;
    return p;
  };
  unsigned long long* R = (unsigned long long*)alloc((size_t)7 * N * 8);
  uint8_t* m8 = (uint8_t*)alloc((size_t)N * 64);
  int* dflag = (int*)alloc(256);
  int* cnt = (int*)alloc((size_t)N * 4);
  int* row_ptr = (int*)alloc((size_t)(N + 1) * 4);
  int* cursor = (int*)alloc((size_t)N * 4);
  int* dst_csr = (int*)alloc((size_t)E * 4);
  int* bsum = (int*)alloc(256 * 4);
  int* ebsum = (int*)alloc(256 * 4);
  float* pw = (float*)alloc((size_t)N * 64 * 4);
  float* sinv = (float*)alloc((size_t)N * 64 * 4);
  float* zA = (float*)alloc((size_t)N * 64 * 4);
  float* zB = (float*)alloc((size_t)N * 64 * 4);
  float* musum = (float*)alloc(256);
  float* mu = (float*)alloc(256);
  float* C = (float*)alloc(64 * 64 * 4);
  float* cor = (float*)alloc(64 * 64 * 4);

  int gN = (N + 255) / 256;
  int gE = (E + 255) / 256;
  int total = N * 64;
  int gT = (total + 255) / 256;  // one wave per node
  int NB = (N + 255) / 256;      // scan chunks (<=256)

  // 0. normalize mask dtype
  hipMemsetAsync(dflag, 0, 4, stream);
  k_detect<<<gT, 256, 0, stream>>>(mask_raw, total, dflag);
  k_norm<<<gT, 256, 0, stream>>>(mask_raw, m8, total, dflag);

  // 1. CSR by row (needed by pull-BFS too)
  hipMemsetAsync(cnt, 0, (size_t)N * 4, stream);
  k_count<<<gE, 256, 0, stream>>>(row, cnt, E);
  k_bsum<<<NB, 256, 0, stream>>>(cnt, bsum, N);
  k_bscan<<<1, 256, 0, stream>>>(bsum, ebsum, row_ptr + N, NB);
  k_chscan<<<NB, 256, 0, stream>>>(cnt, ebsum, row_ptr, cursor, N);
  k_scatter<<<gE, 256, 0, stream>>>(row, col, cursor, dst_csr, E);

  // 2. per-channel BFS, pull mode (no atomics, no copies)
  k_init_masks<<<gN, 256, 0, stream>>>(m8, R, N);
  for (int h = 0; h < 6; ++h)
    k_bfs_pull<<<gN, 256, 0, stream>>>(row_ptr, dst_csr, R + (size_t)h * N,
                                       R + (size_t)(h + 1) * N, N);
  k_distpw<<<gT, 256, 0, stream>>>(R, pw, N);

  // 3. row-sum normalization (alpha^(1-d_row) cancels analytically)
  k_sinv<<<gT, 256, 0, stream>>>(row_ptr, dst_csr, pw, sinv, N);

  // 4. 8 propagation iterations on z = pw*o state
  k_init_z<<<gT, 256, 0, stream>>>(m8, x, pw, zA, total);
  float* zsrc = zA;
  float* zdst = zB;
  for (int it = 0; it < 8; ++it) {
    k_prop_z<<<gT, 256, 0, stream>>>(row_ptr, dst_csr, sinv, pw, m8, x, zsrc,
                                     zdst, N, it == 7 ? 1 : 0);
    float* tmp = zsrc; zsrc = zdst; zdst = tmp;
  }
  float* o = zsrc;  // final o_8

  // 5. correlation
  hipMemsetAsync(musum, 0, 256, stream);
  k_meansum<<<256, 256, 0, stream>>>(o, musum, N);
  k_mu<<<1, 64, 0, stream>>>(musum, mu, N);
  hipMemsetAsync(C, 0, 64 * 64 * 4, stream);
  k_covar<<<256, 256, 0, stream>>>(o, mu, C, N);
  k_cor<<<16, 256, 0, stream>>>(C, cor);

  // 6. fusion -> d_out (tiled GEMM)
  int gF = (N + 63) / 64;
  k_fuse2<<<gF, 256, 0, stream>>>(o, pw, mu, cor, (float*)d_out, N);
}

// Round 5
// 630.051 us; speedup vs baseline: 2.1173x; 1.0463x over previous
//
#include <hip/hip_runtime.h>
#include <stdint.h>

// alpha^(i-5) for i=0..15 (alpha=0.9); pw = alpha^d uses c_tab[d+5]
__device__ __constant__ float c_tab[16] = {
  1.6935087808430286f, 1.5241579027587256f, 1.3717421124828532f,
  1.2345679012345678f, 1.1111111111111112f, 1.0f, 0.9f, 0.81f,
  0.729f, 0.6561f, 0.59049f, 0.531441f, 0.4782969f, 0.43046721f,
  0.387420489f, 0.3486784401f };

// ---- mask dtype probe: int32-encoded bool has all bytes at (i%4)!=0 == 0 ----
__global__ void k_detect(const uint8_t* __restrict__ m, int nbytes,
                         int* __restrict__ flag) {
  int i = blockIdx.x * blockDim.x + threadIdx.x;
  if (i < nbytes && (i & 3) && m[i]) atomicOr(flag, 1);
}

// ---- build initial 64-bit reach masks straight from the raw mask ----
__global__ void k_init_masks(const uint8_t* __restrict__ raw,
                             const int* __restrict__ flag,
                             unsigned long long* __restrict__ R, int N) {
  int n = blockIdx.x * blockDim.x + threadIdx.x;
  if (n >= N) return;
  unsigned long long r = 0;
  if (*flag) {  // u8/bool wire format
    const unsigned long long* m8 =
        (const unsigned long long*)(raw + (size_t)n * 64);
#pragma unroll
    for (int q = 0; q < 8; ++q) {
      unsigned long long v = m8[q] & 0x0101010101010101ULL;
      unsigned long long byte = (v * 0x0102040810204080ULL) >> 56;
      r |= byte << (8 * q);
    }
  } else {  // int32 wire format
    const int* mi = (const int*)raw + (size_t)n * 64;
#pragma unroll
    for (int f = 0; f < 64; ++f)
      if (mi[f]) r |= 1ULL << f;
  }
  R[n] = r;
}

// ---- pull-mode BFS hop with saturation early-exit ----
__global__ void k_bfs_pull(const int* __restrict__ row_ptr,
                           const int* __restrict__ dst_csr,
                           const unsigned long long* __restrict__ Rold,
                           unsigned long long* __restrict__ Rnew, int N) {
  int n = blockIdx.x * blockDim.x + threadIdx.x;
  if (n >= N) return;
  unsigned long long r = Rold[n];
  if (r == ~0ULL) { Rnew[n] = r; return; }  // saturated: neighbors add nothing
  int s = row_ptr[n], s1 = row_ptr[n + 1];
  for (; s + 8 <= s1; s += 8) {
    int d0 = dst_csr[s], d1 = dst_csr[s+1], d2 = dst_csr[s+2], d3 = dst_csr[s+3];
    int d4 = dst_csr[s+4], d5 = dst_csr[s+5], d6 = dst_csr[s+6], d7 = dst_csr[s+7];
    unsigned long long r0 = Rold[d0] | Rold[d1];
    unsigned long long r1 = Rold[d2] | Rold[d3];
    unsigned long long r2 = Rold[d4] | Rold[d5];
    unsigned long long r3 = Rold[d6] | Rold[d7];
    r |= (r0 | r1) | (r2 | r3);
  }
  for (; s < s1; ++s) r |= Rold[dst_csr[s]];
  Rnew[n] = r;
}

// ---- dist -> pw = alpha^d, and z0 = obs ? pw*x : 0 (merged) ----
__global__ void k_distpw_z(const unsigned long long* __restrict__ R,
                           const float* __restrict__ x,
                           float* __restrict__ pw, float* __restrict__ z, int N) {
  int wave = (blockIdx.x * blockDim.x + threadIdx.x) >> 6;
  int lane = threadIdx.x & 63;
  if (wave >= N) return;
  int d = 0;
#pragma unroll
  for (int h = 0; h < 6; ++h)
    d += (int)((~R[(size_t)h * N + wave] >> lane) & 1ULL);
  if (!((R[(size_t)6 * N + wave] >> lane) & 1ULL)) d = 0;  // unreached -> 0
  float p = c_tab[d + 5];
  size_t ni = (size_t)wave * 64 + lane;
  pw[ni] = p;
  bool obs = (R[wave] >> lane) & 1ULL;  // hop-0 mask bit
  z[ni] = obs ? p * x[ni] : 0.f;
}

// ---- CSR build ----
__global__ void k_count(const int* __restrict__ row, int* __restrict__ cnt, int E) {
  int e = blockIdx.x * blockDim.x + threadIdx.x;
  if (e < E) atomicAdd(&cnt[row[e]], 1);
}

__global__ void k_bsum(const int* __restrict__ cnt, int* __restrict__ bsum, int N) {
  __shared__ int sm[256];
  int b = blockIdx.x, t = threadIdx.x;
  int i = b * 256 + t;
  int v = (i < N) ? cnt[i] : 0;
  sm[t] = v;
  __syncthreads();
  for (int off = 128; off > 0; off >>= 1) {
    if (t < off) sm[t] += sm[t + off];
    __syncthreads();
  }
  if (t == 0) bsum[b] = sm[0];
}

__global__ void k_bscan(const int* __restrict__ bsum, int* __restrict__ ebsum,
                        int* __restrict__ row_ptr_N, int NB) {
  __shared__ int sm[256];
  int t = threadIdx.x;
  int v = (t < NB) ? bsum[t] : 0;
  sm[t] = v;
  __syncthreads();
  for (int off = 1; off < 256; off <<= 1) {
    int tv = (t >= off) ? sm[t - off] : 0;
    __syncthreads();
    sm[t] += tv;
    __syncthreads();
  }
  if (t < NB) ebsum[t] = sm[t] - v;
  if (t == 255) *row_ptr_N = sm[255];
}

__global__ void k_chscan(const int* __restrict__ cnt, const int* __restrict__ ebsum,
                         int* __restrict__ row_ptr, int* __restrict__ cursor, int N) {
  __shared__ int sm[256];
  int b = blockIdx.x, t = threadIdx.x;
  int i = b * 256 + t;
  int v = (i < N) ? cnt[i] : 0;
  sm[t] = v;
  __syncthreads();
  for (int off = 1; off < 256; off <<= 1) {
    int tv = (t >= off) ? sm[t - off] : 0;
    __syncthreads();
    sm[t] += tv;
    __syncthreads();
  }
  if (i < N) {
    int ex = ebsum[b] + sm[t] - v;
    row_ptr[i] = ex;
    cursor[i] = ex;
  }
}

__global__ void k_scatter(const int* __restrict__ row, const int* __restrict__ col,
                          int* __restrict__ cursor, int* __restrict__ dst_csr, int E) {
  int e = blockIdx.x * blockDim.x + threadIdx.x;
  if (e >= E) return;
  int pos = atomicAdd(&cursor[row[e]], 1);
  dst_csr[pos] = col[e];
}

// ---- sinv[n][f] = 1 / sum_{dst in CSR[n]} pw[dst][f] ----
__global__ void k_sinv(const int* __restrict__ row_ptr, const int* __restrict__ dst_csr,
                       const float* __restrict__ pw, float* __restrict__ sinv, int N) {
  int wave = (blockIdx.x * blockDim.x + threadIdx.x) >> 6;
  int lane = threadIdx.x & 63;
  if (wave >= N) return;
  int s = row_ptr[wave], s1 = row_ptr[wave + 1];
  float a0 = 0.f, a1 = 0.f;
  for (; s + 8 <= s1; s += 8) {
    int d0 = dst_csr[s], d1 = dst_csr[s+1], d2 = dst_csr[s+2], d3 = dst_csr[s+3];
    int d4 = dst_csr[s+4], d5 = dst_csr[s+5], d6 = dst_csr[s+6], d7 = dst_csr[s+7];
    a0 += pw[(size_t)d0 * 64 + lane] + pw[(size_t)d1 * 64 + lane] +
          pw[(size_t)d2 * 64 + lane] + pw[(size_t)d3 * 64 + lane];
    a1 += pw[(size_t)d4 * 64 + lane] + pw[(size_t)d5 * 64 + lane] +
          pw[(size_t)d6 * 64 + lane] + pw[(size_t)d7 * 64 + lane];
  }
  for (; s < s1; ++s) a0 += pw[(size_t)dst_csr[s] * 64 + lane];
  float acc = a0 + a1;
  sinv[(size_t)wave * 64 + lane] = (acc > 0.f) ? (1.f / acc) : 0.f;
}

// ---- propagation on z-state; observed bit comes from R0 (8B/node) ----
__global__ void k_prop_z(const int* __restrict__ row_ptr, const int* __restrict__ dst_csr,
                         const float* __restrict__ sinv, const float* __restrict__ pw,
                         const unsigned long long* __restrict__ R0,
                         const float* __restrict__ x,
                         const float* __restrict__ z_prev, float* __restrict__ out,
                         int N, int write_o) {
  int wave = (blockIdx.x * blockDim.x + threadIdx.x) >> 6;
  int lane = threadIdx.x & 63;
  if (wave >= N) return;
  size_t ni = (size_t)wave * 64 + lane;
  int s = row_ptr[wave], s1 = row_ptr[wave + 1];
  float a0 = 0.f, a1 = 0.f;
  for (; s + 8 <= s1; s += 8) {
    int d0 = dst_csr[s], d1 = dst_csr[s+1], d2 = dst_csr[s+2], d3 = dst_csr[s+3];
    int d4 = dst_csr[s+4], d5 = dst_csr[s+5], d6 = dst_csr[s+6], d7 = dst_csr[s+7];
    float b0 = z_prev[(size_t)d0 * 64 + lane] + z_prev[(size_t)d1 * 64 + lane];
    float b1 = z_prev[(size_t)d2 * 64 + lane] + z_prev[(size_t)d3 * 64 + lane];
    float b2 = z_prev[(size_t)d4 * 64 + lane] + z_prev[(size_t)d5 * 64 + lane];
    float b3 = z_prev[(size_t)d6 * 64 + lane] + z_prev[(size_t)d7 * 64 + lane];
    a0 += b0 + b1;
    a1 += b2 + b3;
  }
  for (; s < s1; ++s) a0 += z_prev[(size_t)dst_csr[s] * 64 + lane];
  float v = (a0 + a1) * sinv[ni];
  bool obs = (R0[wave] >> lane) & 1ULL;
  float ov = obs ? x[ni] : v;
  out[ni] = write_o ? ov : pw[ni] * ov;
}

// ---- uncentered second moment M2 = sum o o^T and column sums (fused) ----
__global__ void k_covar(const float* __restrict__ o, float* __restrict__ M2,
                        float* __restrict__ musum, int N) {
  __shared__ float yt[32][68];  // pad 68: 16B-aligned rows, 2-way bank alias (free)
  int t = threadIdx.x;
  int i0 = (t >> 4) * 4, j0 = (t & 15) * 4;
  float acc[4][4] = {};
  float csum = 0.f;  // this thread always stages column (t&63)
  for (size_t base = (size_t)blockIdx.x * 32; base < (size_t)N;
       base += (size_t)gridDim.x * 32) {
    int rows = min(32, N - (int)base);
    for (int k = t; k < rows * 64; k += 256) {
      int nn = k >> 6, f = k & 63;
      float val = o[(base + nn) * 64 + f];
      yt[nn][f] = val;
      csum += val;
    }
    __syncthreads();
    for (int nn = 0; nn < rows; ++nn) {
      float4 a = *(const float4*)&yt[nn][i0];
      float4 b = *(const float4*)&yt[nn][j0];
      acc[0][0] += a.x * b.x; acc[0][1] += a.x * b.y; acc[0][2] += a.x * b.z; acc[0][3] += a.x * b.w;
      acc[1][0] += a.y * b.x; acc[1][1] += a.y * b.y; acc[1][2] += a.y * b.z; acc[1][3] += a.y * b.w;
      acc[2][0] += a.z * b.x; acc[2][1] += a.z * b.y; acc[2][2] += a.z * b.z; acc[2][3] += a.z * b.w;
      acc[3][0] += a.w * b.x; acc[3][1] += a.w * b.y; acc[3][2] += a.w * b.z; acc[3][3] += a.w * b.w;
    }
    __syncthreads();
  }
#pragma unroll
  for (int a = 0; a < 4; ++a)
#pragma unroll
    for (int b = 0; b < 4; ++b)
      atomicAdd(&M2[(size_t)(i0 + a) * 64 + j0 + b], acc[a][b]);
  atomicAdd(&musum[t & 63], csum);
}

// ---- cor from uncentered moments: C = M2 - N mu mu^T ----
__global__ void k_cor(const float* __restrict__ M2, const float* __restrict__ musum,
                      float* __restrict__ cor, int N) {
  int idx = blockIdx.x * blockDim.x + threadIdx.x;
  if (idx >= 4096) return;
  int i = idx >> 6, j = idx & 63;
  float inv_n = 1.f / (float)N;
  float mi = musum[i] * inv_n, mj = musum[j] * inv_n;
  float Cij = M2[idx] - (float)N * mi * mj;
  float Cii = M2[i * 64 + i] - (float)N * mi * mi;
  float Cjj = M2[j * 64 + j] - (float)N * mj * mj;
  float d = sqrtf(Cii * Cjj);
  cor[idx] = (i != j && d > 0.f) ? (Cij / d) : 0.f;  // nan_to_num + zero diag
}

// ---- fusion as tiled GEMM: out = o + 0.5*(1-pw)*((pw*(o-mu)) @ cor) ----
__global__ void k_fuse2(const float* __restrict__ o, const float* __restrict__ pw,
                        const float* __restrict__ musum, const float* __restrict__ cor,
                        float* __restrict__ out, int N) {
  __shared__ float a1t[64][65];
  __shared__ float scor[64][65];
  __shared__ float smu[64];
  int t = threadIdx.x;
  int nbase = blockIdx.x * 64;
  if (t < 64) smu[t] = musum[t] / (float)N;
#pragma unroll
  for (int j = 0; j < 16; ++j) {
    int idx = t + 256 * j;
    scor[idx >> 6][idx & 63] = cor[idx];
  }
  __syncthreads();
#pragma unroll
  for (int j = 0; j < 16; ++j) {
    int idx = t + 256 * j;
    int r = idx >> 6, c = idx & 63;
    int n = nbase + r;
    float val = 0.f;
    if (n < N) {
      size_t g = (size_t)n * 64 + c;
      val = pw[g] * (o[g] - smu[c]);
    }
    a1t[r][c] = val;
  }
  __syncthreads();
  int tr = (t >> 4) * 4, tc = (t & 15) * 4;
  float acc[4][4] = {};
  for (int k = 0; k < 64; ++k) {
    float a[4], b[4];
#pragma unroll
    for (int i = 0; i < 4; ++i) a[i] = a1t[tr + i][k];
#pragma unroll
    for (int j = 0; j < 4; ++j) b[j] = scor[k][tc + j];
#pragma unroll
    for (int i = 0; i < 4; ++i)
#pragma unroll
      for (int j = 0; j < 4; ++j) acc[i][j] += a[i] * b[j];
  }
#pragma unroll
  for (int i = 0; i < 4; ++i) {
    int n = nbase + tr + i;
    if (n < N) {
#pragma unroll
      for (int j = 0; j < 4; ++j) {
        size_t g = (size_t)n * 64 + tc + j;
        float p = pw[g];
        out[g] = o[g] + 0.5f * (1.f - p) * acc[i][j];
      }
    }
  }
}

extern "C" void kernel_launch(void* const* d_in, const int* in_sizes, int n_in,
                              void* d_out, int out_size, void* d_ws, size_t ws_size,
                              hipStream_t stream) {
  const float* x = (const float*)d_in[0];
  const int* ei = (const int*)d_in[1];
  const uint8_t* mask_raw = (const uint8_t*)d_in[2];
  int N = in_sizes[0] / 64;   // 50000
  int E = in_sizes[1] / 2;    // 800000
  const int* row = ei;
  const int* col = ei + E;

  char* w = (char*)d_ws;
  size_t off = 0;
  auto alloc = [&](size_t bytes) -> void* {
    void* p = w + off;
    off += (bytes + 255) & ~(size_t)255;
    return p;
  };
  unsigned long long* R = (unsigned long long*)alloc((size_t)7 * N * 8);
  int* dflag = (int*)alloc(256);
  int* cnt = (int*)alloc((size_t)N * 4);
  int* row_ptr = (int*)alloc((size_t)(N + 1) * 4);
  int* cursor = (int*)alloc((size_t)N * 4);
  int* dst_csr = (int*)alloc((size_t)E * 4);
  int* bsum = (int*)alloc(256 * 4);
  int* ebsum = (int*)alloc(256 * 4);
  float* pw = (float*)alloc((size_t)N * 64 * 4);
  float* sinv = (float*)alloc((size_t)N * 64 * 4);
  float* zA = (float*)alloc((size_t)N * 64 * 4);
  float* zB = (float*)alloc((size_t)N * 64 * 4);
  float* M2 = (float*)alloc(64 * 64 * 4 + 256);  // M2 then musum, one memset
  float* musum = M2 + 4096;
  float* cor = (float*)alloc(64 * 64 * 4);

  int gN = (N + 255) / 256;
  int gE = (E + 255) / 256;
  int total = N * 64;
  int gT = (total + 255) / 256;  // one wave per node
  int NB = (N + 255) / 256;      // scan chunks (<=256)

  // 0. probe mask dtype, build hop-0 reach masks directly from raw
  hipMemsetAsync(dflag, 0, 4, stream);
  k_detect<<<gT, 256, 0, stream>>>(mask_raw, total, dflag);
  k_init_masks<<<gN, 256, 0, stream>>>(mask_raw, dflag, R, N);

  // 1. CSR by row
  hipMemsetAsync(cnt, 0, (size_t)N * 4, stream);
  k_count<<<gE, 256, 0, stream>>>(row, cnt, E);
  k_bsum<<<NB, 256, 0, stream>>>(cnt, bsum, N);
  k_bscan<<<1, 256, 0, stream>>>(bsum, ebsum, row_ptr + N, NB);
  k_chscan<<<NB, 256, 0, stream>>>(cnt, ebsum, row_ptr, cursor, N);
  k_scatter<<<gE, 256, 0, stream>>>(row, col, cursor, dst_csr, E);

  // 2. per-channel BFS, pull mode with saturation early-exit
  for (int h = 0; h < 6; ++h)
    k_bfs_pull<<<gN, 256, 0, stream>>>(row_ptr, dst_csr, R + (size_t)h * N,
                                       R + (size_t)(h + 1) * N, N);
  // 3. pw = alpha^d and z0 in one pass
  k_distpw_z<<<gT, 256, 0, stream>>>(R, x, pw, zA, N);

  // 4. row-sum normalization (alpha^(1-d_row) cancels analytically)
  k_sinv<<<gT, 256, 0, stream>>>(row_ptr, dst_csr, pw, sinv, N);

  // 5. 8 propagation iterations on z = pw*o state
  float* zsrc = zA;
  float* zdst = zB;
  for (int it = 0; it < 8; ++it) {
    k_prop_z<<<gT, 256, 0, stream>>>(row_ptr, dst_csr, sinv, pw, R, x, zsrc,
                                     zdst, N, it == 7 ? 1 : 0);
    float* tmp = zsrc; zsrc = zdst; zdst = tmp;
  }
  float* o = zsrc;  // final o_8

  // 6. correlation from uncentered moments (mean fused into covar)
  hipMemsetAsync(M2, 0, 64 * 64 * 4 + 256, stream);
  k_covar<<<512, 256, 0, stream>>>(o, M2, musum, N);
  k_cor<<<16, 256, 0, stream>>>(M2, musum, cor, N);

  // 7. fusion -> d_out (tiled GEMM)
  int gF = (N + 63) / 64;
  k_fuse2<<<gF, 256, 0, stream>>>(o, pw, musum, cor, (float*)d_out, N);
}